// Round 1
// baseline (228.436 us; speedup 1.0000x reference)
//
#include <hip/hip_runtime.h>
#include <hip/hip_bf16.h>
#include <stdint.h>

// Problem constants
#define BB 8
#define SS 2048
#define NEXP 16
#define DIN 1024
#define DOUT 1024

typedef short bf16x8 __attribute__((ext_vector_type(8)));
typedef float floatx4 __attribute__((ext_vector_type(4)));

// fp32 -> bf16 round-to-nearest-even (bit trick; inputs are normal floats)
__device__ __forceinline__ unsigned short f2bf(float f) {
    union { float f; unsigned int u; } v; v.f = f;
    unsigned int u = v.u;
    unsigned int r = u + 0x7FFFu + ((u >> 16) & 1u);
    return (unsigned short)(r >> 16);
}

// async global->LDS, 16B per lane. LDS dest = wave-uniform base + lane*16.
__device__ __forceinline__ void gload16(const void* g, void* l) {
    __builtin_amdgcn_global_load_lds(
        (const __attribute__((address_space(1))) void*)g,
        (__attribute__((address_space(3))) void*)l,
        16, 0, 0);
}

// ---------------------------------------------------------------------------
// Kernel 1: prep.
//  job A: convert x [B,S,DIN] fp32 -> bf16            (2,097,152 threads, 8 elem each)
//  job B: mixed_w[b] = sum_n p[b,n] W[n] -> bf16      (  262,144 threads, 4 elem x 8 batches)
//  job C: mixed_b[b] = sum_n p[b,n] bias[n] (fp32)    (    8,192 threads)
// ---------------------------------------------------------------------------
__global__ __launch_bounds__(256) void prep_kernel(
    const float* __restrict__ x, const float* __restrict__ p,
    const float* __restrict__ w, const float* __restrict__ bias,
    unsigned short* __restrict__ xb, unsigned short* __restrict__ mw,
    float* __restrict__ mb)
{
    __shared__ float sp[BB * NEXP];
    const int tid = threadIdx.x;
    if (tid < BB * NEXP) sp[tid] = p[tid];
    __syncthreads();

    const long gid = (long)blockIdx.x * 256 + tid;
    const long NX = (long)BB * SS * DIN / 8;   // 2,097,152
    const long NW = (long)DOUT * DIN / 4;      //   262,144
    const long NB = (long)BB * DOUT;           //     8,192

    if (gid < NX) {
        const float4* xv = (const float4*)x;
        float4 v0 = xv[gid * 2 + 0];
        float4 v1 = xv[gid * 2 + 1];
        uint4 o;
        o.x = (unsigned)f2bf(v0.x) | ((unsigned)f2bf(v0.y) << 16);
        o.y = (unsigned)f2bf(v0.z) | ((unsigned)f2bf(v0.w) << 16);
        o.z = (unsigned)f2bf(v1.x) | ((unsigned)f2bf(v1.y) << 16);
        o.w = (unsigned)f2bf(v1.z) | ((unsigned)f2bf(v1.w) << 16);
        ((uint4*)xb)[gid] = o;
    } else if (gid < NX + NW) {
        const long t = gid - NX;
        const long j4 = t * 4;            // flat index into [DOUT*DIN)
        float acc[BB][4];
        #pragma unroll
        for (int b = 0; b < BB; ++b)
            #pragma unroll
            for (int k = 0; k < 4; ++k) acc[b][k] = 0.f;
        #pragma unroll
        for (int n = 0; n < NEXP; ++n) {
            float4 wv = *(const float4*)(w + (long)n * DOUT * DIN + j4);
            #pragma unroll
            for (int b = 0; b < BB; ++b) {
                float pb = sp[b * NEXP + n];
                acc[b][0] += pb * wv.x; acc[b][1] += pb * wv.y;
                acc[b][2] += pb * wv.z; acc[b][3] += pb * wv.w;
            }
        }
        #pragma unroll
        for (int b = 0; b < BB; ++b) {
            uint2 o;
            o.x = (unsigned)f2bf(acc[b][0]) | ((unsigned)f2bf(acc[b][1]) << 16);
            o.y = (unsigned)f2bf(acc[b][2]) | ((unsigned)f2bf(acc[b][3]) << 16);
            *(uint2*)(mw + (long)b * DOUT * DIN + j4) = o;
        }
    } else if (gid < NX + NW + NB) {
        const long t = gid - NX - NW;
        const int b = (int)(t >> 10), i = (int)(t & 1023);
        float s = 0.f;
        #pragma unroll
        for (int n = 0; n < NEXP; ++n) s += sp[b * NEXP + n] * bias[n * DOUT + i];
        mb[t] = s;
    }
}

// ---------------------------------------------------------------------------
// Kernel 2: batched GEMM  out[b] = x_bf16[b] (S x K) * mixed_w[b]^T (K x DOUT) + mixed_b[b]
// m97 structure: 128x128 block tile, BK=64, 256 threads (4 waves, each 64x64),
// 16x16x32 bf16 MFMA, global_load_lds width-16 staging, single LDS buffer.
// ---------------------------------------------------------------------------
__global__ __launch_bounds__(256) void gemm_kernel(
    const unsigned short* __restrict__ xb,   // [B][S][DIN] bf16
    const unsigned short* __restrict__ mw,   // [B][DOUT][DIN] bf16
    const float* __restrict__ mb,            // [B][DOUT] fp32
    float* __restrict__ out)                 // [B][S][DOUT] fp32
{
    __shared__ __align__(16) unsigned short sA[128 * 64];  // 16 KB
    __shared__ __align__(16) unsigned short sB[128 * 64];  // 16 KB

    const int tid  = threadIdx.x;
    const int wave = tid >> 6;
    const int lane = tid & 63;
    const int b    = blockIdx.z;
    const int tileM = blockIdx.y * 128;   // over S
    const int tileN = blockIdx.x * 128;   // over DOUT

    const unsigned short* Ag = xb + (long)b * SS * DIN;
    const unsigned short* Bg = mw + (long)b * DOUT * DIN;

    const int q     = lane >> 4;     // quad 0..3
    const int r16   = lane & 15;
    const int mBase = 64 * (wave >> 1);
    const int nBase = 64 * (wave & 1);

    // staging: each wave owns 4 chunks of 1KB (8 rows x 64 bf16) for A and B
    const int sRow = (lane >> 3);        // 0..7 within chunk
    const int sCol = (lane & 7) * 8;     // element offset within row

    floatx4 acc[4][4];
    #pragma unroll
    for (int mi = 0; mi < 4; ++mi)
        #pragma unroll
        for (int ni = 0; ni < 4; ++ni)
            acc[mi][ni] = (floatx4){0.f, 0.f, 0.f, 0.f};

    for (int k0 = 0; k0 < DIN; k0 += 64) {
        __syncthreads();   // previous tile's compute done before overwrite
        #pragma unroll
        for (int c = 0; c < 4; ++c) {
            const int chunk = wave * 4 + c;          // 0..15
            const int row   = chunk * 8 + sRow;      // 0..127
            gload16(Ag + (long)(tileM + row) * DIN + k0 + sCol, &sA[chunk * 512]);
            gload16(Bg + (long)(tileN + row) * DIN + k0 + sCol, &sB[chunk * 512]);
        }
        __syncthreads();   // loads visible (compiler drains vmcnt before barrier)

        #pragma unroll
        for (int kk = 0; kk < 64; kk += 32) {
            bf16x8 af[4], bfv[4];
            #pragma unroll
            for (int i = 0; i < 4; ++i)
                af[i] = *(const bf16x8*)&sA[(mBase + 16 * i + r16) * 64 + kk + q * 8];
            #pragma unroll
            for (int i = 0; i < 4; ++i)
                bfv[i] = *(const bf16x8*)&sB[(nBase + 16 * i + r16) * 64 + kk + q * 8];
            #pragma unroll
            for (int mi = 0; mi < 4; ++mi)
                #pragma unroll
                for (int ni = 0; ni < 4; ++ni)
                    acc[mi][ni] = __builtin_amdgcn_mfma_f32_16x16x32_bf16(
                        af[mi], bfv[ni], acc[mi][ni], 0, 0, 0);
        }
    }

    // epilogue: C[m][n] = acc + mixed_b[b][n]
    float bv[4];
    #pragma unroll
    for (int ni = 0; ni < 4; ++ni)
        bv[ni] = mb[b * DOUT + tileN + nBase + 16 * ni + r16];

    #pragma unroll
    for (int mi = 0; mi < 4; ++mi) {
        #pragma unroll
        for (int rr = 0; rr < 4; ++rr) {
            const int row = tileM + mBase + 16 * mi + q * 4 + rr;
            float* orow = out + (long)b * SS * DOUT + (long)row * DOUT;
            #pragma unroll
            for (int ni = 0; ni < 4; ++ni)
                orow[tileN + nBase + 16 * ni + r16] = acc[mi][ni][rr] + bv[ni];
        }
    }
}

extern "C" void kernel_launch(void* const* d_in, const int* in_sizes, int n_in,
                              void* d_out, int out_size, void* d_ws, size_t ws_size,
                              hipStream_t stream) {
    const float* x    = (const float*)d_in[0];   // [8,2048,1024]
    const float* p    = (const float*)d_in[1];   // [8,16]
    const float* w    = (const float*)d_in[2];   // [16,1024,1024]
    const float* bias = (const float*)d_in[3];   // [16,1024]
    float* out = (float*)d_out;                  // [8,2048,1024]

    // workspace layout: x_bf16 (32 MiB) | mixed_w bf16 (16 MiB) | mixed_b fp32 (32 KiB)
    unsigned short* xb = (unsigned short*)d_ws;
    unsigned short* mw = (unsigned short*)((char*)d_ws + (size_t)33554432);
    float*          mb = (float*)((char*)d_ws + (size_t)33554432 + 16777216);

    const long total = 2097152L + 262144L + 8192L;   // 9248 blocks exactly
    dim3 pgrid((unsigned)((total + 255) / 256));
    prep_kernel<<<pgrid, 256, 0, stream>>>(x, p, w, bias, xb, mw, mb);

    dim3 ggrid(DOUT / 128, SS / 128, BB);            // (8,16,8) = 1024 blocks
    gemm_kernel<<<ggrid, 256, 0, stream>>>(xb, mw, mb, out);
}

// Round 2
// 225.022 us; speedup vs baseline: 1.0152x; 1.0152x over previous
//
#include <hip/hip_runtime.h>
#include <hip/hip_bf16.h>
#include <stdint.h>

// Problem constants
#define BB 8
#define SS 2048
#define NEXP 16
#define DIN 1024
#define DOUT 1024

typedef short bf16x8 __attribute__((ext_vector_type(8)));
typedef float floatx4 __attribute__((ext_vector_type(4)));

// fp32 -> bf16 round-to-nearest-even (bit trick; inputs are normal floats)
__device__ __forceinline__ unsigned short f2bf(float f) {
    union { float f; unsigned int u; } v; v.f = f;
    unsigned int u = v.u;
    unsigned int r = u + 0x7FFFu + ((u >> 16) & 1u);
    return (unsigned short)(r >> 16);
}

// async global->LDS, 16B per lane. LDS dest = wave-uniform base + lane*16.
__device__ __forceinline__ void gload16(const void* g, void* l) {
    __builtin_amdgcn_global_load_lds(
        (const __attribute__((address_space(1))) void*)g,
        (__attribute__((address_space(3))) void*)l,
        16, 0, 0);
}

// ---------------------------------------------------------------------------
// Kernel 1a: x fp32 -> bf16 (blocks 0..8191), + mixed bias (blocks 8192..8223)
// ---------------------------------------------------------------------------
__global__ __launch_bounds__(256) void xconv_kernel(
    const float* __restrict__ x, const float* __restrict__ p,
    const float* __restrict__ bias,
    unsigned short* __restrict__ xb, float* __restrict__ mb)
{
    const long gid = (long)blockIdx.x * 256 + threadIdx.x;
    const long NX = (long)BB * SS * DIN / 8;   // 2,097,152 threads, 8 elem each
    if (gid < NX) {
        const float4* xv = (const float4*)x;
        float4 v0 = xv[gid * 2 + 0];
        float4 v1 = xv[gid * 2 + 1];
        uint4 o;
        o.x = (unsigned)f2bf(v0.x) | ((unsigned)f2bf(v0.y) << 16);
        o.y = (unsigned)f2bf(v0.z) | ((unsigned)f2bf(v0.w) << 16);
        o.z = (unsigned)f2bf(v1.x) | ((unsigned)f2bf(v1.y) << 16);
        o.w = (unsigned)f2bf(v1.z) | ((unsigned)f2bf(v1.w) << 16);
        ((uint4*)xb)[gid] = o;
    } else {
        const long t = gid - NX;               // 0..8191: mixed bias
        if (t < (long)BB * DOUT) {
            const int b = (int)(t >> 10), i = (int)(t & 1023);
            float s = 0.f;
            #pragma unroll
            for (int n = 0; n < NEXP; ++n) s += p[b * NEXP + n] * bias[n * DOUT + i];
            mb[t] = s;
        }
    }
}

// ---------------------------------------------------------------------------
// Kernel 1b: mixed_w[b] = sum_n p[b,n] W[n] -> bf16.  262,144 threads,
// each handles 4 consecutive elements for all 8 batches (reads W once).
// ---------------------------------------------------------------------------
__global__ __launch_bounds__(256) void wmix_kernel(
    const float* __restrict__ p, const float* __restrict__ w,
    unsigned short* __restrict__ mw)
{
    __shared__ float sp[BB * NEXP];
    const int tid = threadIdx.x;
    if (tid < BB * NEXP) sp[tid] = p[tid];
    __syncthreads();

    const long t  = (long)blockIdx.x * 256 + tid;   // 0..262143
    const long j4 = t * 4;
    float acc[BB][4];
    #pragma unroll
    for (int b = 0; b < BB; ++b)
        #pragma unroll
        for (int k = 0; k < 4; ++k) acc[b][k] = 0.f;
    #pragma unroll
    for (int n = 0; n < NEXP; ++n) {
        float4 wv = *(const float4*)(w + (long)n * DOUT * DIN + j4);
        #pragma unroll
        for (int b = 0; b < BB; ++b) {
            float pb = sp[b * NEXP + n];
            acc[b][0] += pb * wv.x; acc[b][1] += pb * wv.y;
            acc[b][2] += pb * wv.z; acc[b][3] += pb * wv.w;
        }
    }
    #pragma unroll
    for (int b = 0; b < BB; ++b) {
        uint2 o;
        o.x = (unsigned)f2bf(acc[b][0]) | ((unsigned)f2bf(acc[b][1]) << 16);
        o.y = (unsigned)f2bf(acc[b][2]) | ((unsigned)f2bf(acc[b][3]) << 16);
        *(uint2*)(mw + (long)b * DOUT * DIN + j4) = o;
    }
}

// ---------------------------------------------------------------------------
// Kernel 2: batched GEMM  out[b] = x_bf16[b] (S x K) * mixed_w[b]^T + mixed_b[b]
// 128x128 tile, BK=64, 4 waves x (4x4 of 16x16x32 bf16 MFMA), width-16
// global_load_lds staging.
// Grid = (B, N, M): linear block id % 8 == batch -> each XCD serves one
// batch; its mw[b] (2MB) + xb[b] (4MB) are L2-resident -> staging from L2
// instead of L3.
// ---------------------------------------------------------------------------
__global__ __launch_bounds__(256) void gemm_kernel(
    const unsigned short* __restrict__ xb,   // [B][S][DIN] bf16
    const unsigned short* __restrict__ mw,   // [B][DOUT][DIN] bf16
    const float* __restrict__ mb,            // [B][DOUT] fp32
    float* __restrict__ out)                 // [B][S][DOUT] fp32
{
    __shared__ __align__(16) unsigned short sA[128 * 64];  // 16 KB
    __shared__ __align__(16) unsigned short sB[128 * 64];  // 16 KB

    const int tid  = threadIdx.x;
    const int wave = tid >> 6;
    const int lane = tid & 63;
    const int b    = blockIdx.x;          // batch -> XCD (id % 8 == b)
    const int tileN = blockIdx.y * 128;   // over DOUT
    const int tileM = blockIdx.z * 128;   // over S

    const unsigned short* Ag = xb + (long)b * SS * DIN;
    const unsigned short* Bg = mw + (long)b * DOUT * DIN;

    const int q     = lane >> 4;     // quad 0..3
    const int r16   = lane & 15;
    const int mBase = 64 * (wave >> 1);
    const int nBase = 64 * (wave & 1);

    // staging: each wave owns 4 chunks of 1KB (8 rows x 64 bf16) for A and B
    const int sRow = (lane >> 3);        // 0..7 within chunk
    const int sCol = (lane & 7) * 8;     // element offset within row

    floatx4 acc[4][4];
    #pragma unroll
    for (int mi = 0; mi < 4; ++mi)
        #pragma unroll
        for (int ni = 0; ni < 4; ++ni)
            acc[mi][ni] = (floatx4){0.f, 0.f, 0.f, 0.f};

    for (int k0 = 0; k0 < DIN; k0 += 64) {
        __syncthreads();   // previous tile's compute done before overwrite
        #pragma unroll
        for (int c = 0; c < 4; ++c) {
            const int chunk = wave * 4 + c;          // 0..15
            const int row   = chunk * 8 + sRow;      // 0..127
            gload16(Ag + (long)(tileM + row) * DIN + k0 + sCol, &sA[chunk * 512]);
            gload16(Bg + (long)(tileN + row) * DIN + k0 + sCol, &sB[chunk * 512]);
        }
        __syncthreads();   // loads visible (compiler drains vmcnt before barrier)

        #pragma unroll
        for (int kk = 0; kk < 64; kk += 32) {
            bf16x8 af[4], bfv[4];
            #pragma unroll
            for (int i = 0; i < 4; ++i)
                af[i] = *(const bf16x8*)&sA[(mBase + 16 * i + r16) * 64 + kk + q * 8];
            #pragma unroll
            for (int i = 0; i < 4; ++i)
                bfv[i] = *(const bf16x8*)&sB[(nBase + 16 * i + r16) * 64 + kk + q * 8];
            #pragma unroll
            for (int mi = 0; mi < 4; ++mi)
                #pragma unroll
                for (int ni = 0; ni < 4; ++ni)
                    acc[mi][ni] = __builtin_amdgcn_mfma_f32_16x16x32_bf16(
                        af[mi], bfv[ni], acc[mi][ni], 0, 0, 0);
        }
    }

    // epilogue: C[m][n] = acc + mixed_b[b][n]
    float bv[4];
    #pragma unroll
    for (int ni = 0; ni < 4; ++ni)
        bv[ni] = mb[b * DOUT + tileN + nBase + 16 * ni + r16];

    #pragma unroll
    for (int mi = 0; mi < 4; ++mi) {
        #pragma unroll
        for (int rr = 0; rr < 4; ++rr) {
            const int row = tileM + mBase + 16 * mi + q * 4 + rr;
            float* orow = out + (long)b * SS * DOUT + (long)row * DOUT;
            #pragma unroll
            for (int ni = 0; ni < 4; ++ni)
                orow[tileN + nBase + 16 * ni + r16] = acc[mi][ni][rr] + bv[ni];
        }
    }
}

extern "C" void kernel_launch(void* const* d_in, const int* in_sizes, int n_in,
                              void* d_out, int out_size, void* d_ws, size_t ws_size,
                              hipStream_t stream) {
    const float* x    = (const float*)d_in[0];   // [8,2048,1024]
    const float* p    = (const float*)d_in[1];   // [8,16]
    const float* w    = (const float*)d_in[2];   // [16,1024,1024]
    const float* bias = (const float*)d_in[3];   // [16,1024]
    float* out = (float*)d_out;                  // [8,2048,1024]

    // workspace layout: x_bf16 (32 MiB) | mixed_w bf16 (16 MiB) | mixed_b fp32 (32 KiB)
    unsigned short* xb = (unsigned short*)d_ws;
    unsigned short* mw = (unsigned short*)((char*)d_ws + (size_t)33554432);
    float*          mb = (float*)((char*)d_ws + (size_t)33554432 + 16777216);

    xconv_kernel<<<dim3(8192 + 32), 256, 0, stream>>>(x, p, bias, xb, mb);
    wmix_kernel<<<dim3(1024), 256, 0, stream>>>(p, w, mw);

    dim3 ggrid(BB, DOUT / 128, SS / 128);        // (8,8,16) = 1024 blocks
    gemm_kernel<<<ggrid, 256, 0, stream>>>(xb, mw, mb, out);
}

// Round 3
// 214.660 us; speedup vs baseline: 1.0642x; 1.0483x over previous
//
#include <hip/hip_runtime.h>
#include <hip/hip_bf16.h>
#include <stdint.h>

// Problem constants
#define BB 8
#define SS 2048
#define NEXP 16
#define DIN 1024
#define DOUT 1024

typedef short bf16x8 __attribute__((ext_vector_type(8)));
typedef float floatx4 __attribute__((ext_vector_type(4)));

// fp32 -> bf16 round-to-nearest-even (bit trick; inputs are normal floats)
__device__ __forceinline__ unsigned short f2bf(float f) {
    union { float f; unsigned int u; } v; v.f = f;
    unsigned int u = v.u;
    unsigned int r = u + 0x7FFFu + ((u >> 16) & 1u);
    return (unsigned short)(r >> 16);
}

// async global->LDS, 16B per lane. LDS dest = wave-uniform base + lane*16.
__device__ __forceinline__ void gload16(const void* g, void* l) {
    __builtin_amdgcn_global_load_lds(
        (const __attribute__((address_space(1))) void*)g,
        (__attribute__((address_space(3))) void*)l,
        16, 0, 0);
}

// ---------------------------------------------------------------------------
// Kernel 1a: x fp32 -> bf16 (blocks 0..8191), + mixed bias (blocks 8192..8223)
// ---------------------------------------------------------------------------
__global__ __launch_bounds__(256) void xconv_kernel(
    const float* __restrict__ x, const float* __restrict__ p,
    const float* __restrict__ bias,
    unsigned short* __restrict__ xb, float* __restrict__ mb)
{
    const long gid = (long)blockIdx.x * 256 + threadIdx.x;
    const long NX = (long)BB * SS * DIN / 8;   // 2,097,152 threads, 8 elem each
    if (gid < NX) {
        const float4* xv = (const float4*)x;
        float4 v0 = xv[gid * 2 + 0];
        float4 v1 = xv[gid * 2 + 1];
        uint4 o;
        o.x = (unsigned)f2bf(v0.x) | ((unsigned)f2bf(v0.y) << 16);
        o.y = (unsigned)f2bf(v0.z) | ((unsigned)f2bf(v0.w) << 16);
        o.z = (unsigned)f2bf(v1.x) | ((unsigned)f2bf(v1.y) << 16);
        o.w = (unsigned)f2bf(v1.z) | ((unsigned)f2bf(v1.w) << 16);
        ((uint4*)xb)[gid] = o;
    } else {
        const long t = gid - NX;               // 0..8191: mixed bias
        if (t < (long)BB * DOUT) {
            const int b = (int)(t >> 10), i = (int)(t & 1023);
            float s = 0.f;
            #pragma unroll
            for (int n = 0; n < NEXP; ++n) s += p[b * NEXP + n] * bias[n * DOUT + i];
            mb[t] = s;
        }
    }
}

// ---------------------------------------------------------------------------
// Kernel 1b: mixed_w[b] = sum_n p[b,n] W[n] -> bf16.  262,144 threads,
// each handles 4 consecutive elements for all 8 batches (reads W once).
// ---------------------------------------------------------------------------
__global__ __launch_bounds__(256) void wmix_kernel(
    const float* __restrict__ p, const float* __restrict__ w,
    unsigned short* __restrict__ mw)
{
    __shared__ float sp[BB * NEXP];
    const int tid = threadIdx.x;
    if (tid < BB * NEXP) sp[tid] = p[tid];
    __syncthreads();

    const long t  = (long)blockIdx.x * 256 + tid;   // 0..262143
    const long j4 = t * 4;
    float acc[BB][4];
    #pragma unroll
    for (int b = 0; b < BB; ++b)
        #pragma unroll
        for (int k = 0; k < 4; ++k) acc[b][k] = 0.f;
    #pragma unroll
    for (int n = 0; n < NEXP; ++n) {
        float4 wv = *(const float4*)(w + (long)n * DOUT * DIN + j4);
        #pragma unroll
        for (int b = 0; b < BB; ++b) {
            float pb = sp[b * NEXP + n];
            acc[b][0] += pb * wv.x; acc[b][1] += pb * wv.y;
            acc[b][2] += pb * wv.z; acc[b][3] += pb * wv.w;
        }
    }
    #pragma unroll
    for (int b = 0; b < BB; ++b) {
        uint2 o;
        o.x = (unsigned)f2bf(acc[b][0]) | ((unsigned)f2bf(acc[b][1]) << 16);
        o.y = (unsigned)f2bf(acc[b][2]) | ((unsigned)f2bf(acc[b][3]) << 16);
        *(uint2*)(mw + (long)b * DOUT * DIN + j4) = o;
    }
}

// ---------------------------------------------------------------------------
// Kernel 2: batched GEMM  out[b] = x_bf16[b] (S x K) * mixed_w[b]^T + mixed_b[b]
// 128x128 tile, BK=64, 4 waves x (4x4 of 16x16x32 bf16 MFMA), width-16
// global_load_lds staging.
// Grid = (B, N, M): linear block id % 8 == batch -> per-XCD L2 residency.
// LDS XOR swizzle: row r's 8 column-groups (16B each) are stored rotated by
// (r&7) -- done by permuting the *global source* column per lane (stays within
// one 128B window -> coalescing intact, global_load_lds lane mapping honored).
// Reader XORs the group index with (row&7): a quad's 16 lanes then cover all
// 8 bank-groups (2 lanes each = conflict-free) instead of 16-way on one group.
// ---------------------------------------------------------------------------
__global__ __launch_bounds__(256) void gemm_kernel(
    const unsigned short* __restrict__ xb,   // [B][S][DIN] bf16
    const unsigned short* __restrict__ mw,   // [B][DOUT][DIN] bf16
    const float* __restrict__ mb,            // [B][DOUT] fp32
    float* __restrict__ out)                 // [B][S][DOUT] fp32
{
    __shared__ __align__(16) unsigned short sA[128 * 64];  // 16 KB
    __shared__ __align__(16) unsigned short sB[128 * 64];  // 16 KB

    const int tid  = threadIdx.x;
    const int wave = tid >> 6;
    const int lane = tid & 63;
    const int b    = blockIdx.x;          // batch -> XCD (id % 8 == b)
    const int tileN = blockIdx.y * 128;   // over DOUT
    const int tileM = blockIdx.z * 128;   // over S

    const unsigned short* Ag = xb + (long)b * SS * DIN;
    const unsigned short* Bg = mw + (long)b * DOUT * DIN;

    const int q     = lane >> 4;     // quad 0..3
    const int r16   = lane & 15;
    const int mBase = 64 * (wave >> 1);
    const int nBase = 64 * (wave & 1);

    // staging: each wave owns 4 chunks of 1KB (8 rows x 64 bf16) for A and B.
    const int sRow = (lane >> 3);                    // 0..7 row within chunk
    const int sColSw = (((lane & 7) ^ sRow) * 8);    // XOR-swizzled source column

    // reader: swizzled group offsets (elements) for this lane's row (r16&7)
    const int swz = (r16 & 7);

    floatx4 acc[4][4];
    #pragma unroll
    for (int mi = 0; mi < 4; ++mi)
        #pragma unroll
        for (int ni = 0; ni < 4; ++ni)
            acc[mi][ni] = (floatx4){0.f, 0.f, 0.f, 0.f};

    for (int k0 = 0; k0 < DIN; k0 += 64) {
        __syncthreads();   // previous tile's compute done before overwrite
        #pragma unroll
        for (int c = 0; c < 4; ++c) {
            const int chunk = wave * 4 + c;          // 0..15
            const int row   = chunk * 8 + sRow;      // 0..127
            gload16(Ag + (long)(tileM + row) * DIN + k0 + sColSw, &sA[chunk * 512]);
            gload16(Bg + (long)(tileN + row) * DIN + k0 + sColSw, &sB[chunk * 512]);
        }
        __syncthreads();   // loads visible (compiler drains vmcnt before barrier)

        #pragma unroll
        for (int kk = 0; kk < 64; kk += 32) {
            // logical group for this quad/kk, then XOR with row swizzle
            const int gA = ((kk >> 3) + q);          // 0..7
            bf16x8 af[4], bfv[4];
            #pragma unroll
            for (int i = 0; i < 4; ++i)
                af[i] = *(const bf16x8*)&sA[(mBase + 16 * i + r16) * 64 + ((gA ^ swz) * 8)];
            #pragma unroll
            for (int i = 0; i < 4; ++i)
                bfv[i] = *(const bf16x8*)&sB[(nBase + 16 * i + r16) * 64 + ((gA ^ swz) * 8)];
            #pragma unroll
            for (int mi = 0; mi < 4; ++mi)
                #pragma unroll
                for (int ni = 0; ni < 4; ++ni)
                    acc[mi][ni] = __builtin_amdgcn_mfma_f32_16x16x32_bf16(
                        af[mi], bfv[ni], acc[mi][ni], 0, 0, 0);
        }
    }

    // epilogue: C[m][n] = acc + mixed_b[b][n]
    float bv[4];
    #pragma unroll
    for (int ni = 0; ni < 4; ++ni)
        bv[ni] = mb[b * DOUT + tileN + nBase + 16 * ni + r16];

    #pragma unroll
    for (int mi = 0; mi < 4; ++mi) {
        #pragma unroll
        for (int rr = 0; rr < 4; ++rr) {
            const int row = tileM + mBase + 16 * mi + q * 4 + rr;
            float* orow = out + (long)b * SS * DOUT + (long)row * DOUT;
            #pragma unroll
            for (int ni = 0; ni < 4; ++ni)
                orow[tileN + nBase + 16 * ni + r16] = acc[mi][ni][rr] + bv[ni];
        }
    }
}

extern "C" void kernel_launch(void* const* d_in, const int* in_sizes, int n_in,
                              void* d_out, int out_size, void* d_ws, size_t ws_size,
                              hipStream_t stream) {
    const float* x    = (const float*)d_in[0];   // [8,2048,1024]
    const float* p    = (const float*)d_in[1];   // [8,16]
    const float* w    = (const float*)d_in[2];   // [16,1024,1024]
    const float* bias = (const float*)d_in[3];   // [16,1024]
    float* out = (float*)d_out;                  // [8,2048,1024]

    // workspace layout: x_bf16 (32 MiB) | mixed_w bf16 (16 MiB) | mixed_b fp32 (32 KiB)
    unsigned short* xb = (unsigned short*)d_ws;
    unsigned short* mw = (unsigned short*)((char*)d_ws + (size_t)33554432);
    float*          mb = (float*)((char*)d_ws + (size_t)33554432 + 16777216);

    xconv_kernel<<<dim3(8192 + 32), 256, 0, stream>>>(x, p, bias, xb, mb);
    wmix_kernel<<<dim3(1024), 256, 0, stream>>>(p, w, mw);

    dim3 ggrid(BB, DOUT / 128, SS / 128);        // (8,8,16) = 1024 blocks
    gemm_kernel<<<ggrid, 256, 0, stream>>>(xb, mw, mb, out);
}